// Round 12
// baseline (401.748 us; speedup 1.0000x reference)
//
#include <hip/hip_runtime.h>
#include <hip/hip_bf16.h>

// Problem constants (B=2, L=2048, D=1024, H=16, HD=64)
#define BB 2
#define LL 2048
#define DD 1024
#define HH 16
#define HDIM 64
#define PSTR 72   // padded P-buffer row stride (elems)

typedef __hip_bfloat16 bf16;
typedef __attribute__((ext_vector_type(8))) __bf16 bf16x8;     // MFMA A/B frag
typedef __attribute__((ext_vector_type(4))) __bf16 bf16x4;     // 8B packed store
typedef __attribute__((ext_vector_type(4))) float f32x4;       // MFMA C/D frag

__device__ inline __bf16 f2b(float f) {
    __hip_bfloat16 h = __float2bfloat16(f);
    return __builtin_bit_cast(__bf16, h);
}
__device__ inline bf16x8 ldb8(const bf16* p) {
    return *(const bf16x8*)(const void*)p;
}
__device__ inline void stb8(bf16* p, bf16x8 v) {
    *(bf16x8*)(void*)p = v;
}

// ---------------------------------------------------------------------------
// Fused f32 -> bf16 convert (streaming) — unchanged.
// ---------------------------------------------------------------------------
__global__ __launch_bounds__(256) void cvt_all(
    const float* __restrict__ w0, const float* __restrict__ w1,
    const float* __restrict__ w2, const float* __restrict__ w3,
    const float* __restrict__ a0, const float* __restrict__ a1,
    const float* __restrict__ a2,
    bf16* __restrict__ ow0, bf16* __restrict__ ow1,
    bf16* __restrict__ ow2, bf16* __restrict__ ow3,
    bf16* __restrict__ oa0, bf16* __restrict__ oa1, bf16* __restrict__ oa2)
{
    const float* in;
    bf16* out;
    int i;
    if (blockIdx.x < 4096) {
        int seg = blockIdx.x >> 10;
        i = ((blockIdx.x & 1023) * 256 + threadIdx.x) * 4;
        in  = seg == 0 ? w0 : seg == 1 ? w1 : seg == 2 ? w2 : w3;
        out = seg == 0 ? ow0 : seg == 1 ? ow1 : seg == 2 ? ow2 : ow3;
    } else {
        int bb = blockIdx.x - 4096;
        int seg = bb >> 12;
        i = ((bb & 4095) * 256 + threadIdx.x) * 4;
        in  = seg == 0 ? a0 : seg == 1 ? a1 : a2;
        out = seg == 0 ? oa0 : seg == 1 ? oa1 : oa2;
    }
    float4 f = *(const float4*)(const void*)(in + i);
    bf16x4 o;
    o[0] = f2b(f.x);
    o[1] = f2b(f.y);
    o[2] = f2b(f.z);
    o[3] = f2b(f.w);
    *(bf16x4*)(void*)(out + i) = o;
}

// ---------------------------------------------------------------------------
// Fused Q/K/V projection. ROUND-20: depth-2 register prefetch. r18's k-loop
// issues the k+1 loads after barrier#2 and waits on them at the NEXT iter's
// stb8 — flight time ~1 MFMA phase (~400cy) < HBM latency (~900cy), so each
// iter eats the uncovered remainder. Unroll x2 with ping-pong reg buffers
// s0/s1: each load is consumed 2 k-steps after issue (2 MFMA phases + 4
// barriers of flight). LDS hazard structure (2 barriers/step, single buffer)
// unchanged. VGPR 40->~64, still >= 6 waves/SIMD under the (256,6) cap.
// ---------------------------------------------------------------------------
__global__ __launch_bounds__(256, 6) void qkv3_gemm(
    const bf16* __restrict__ qa, const bf16* __restrict__ ka,
    const bf16* __restrict__ va,
    const bf16* __restrict__ Wqm, const bf16* __restrict__ Wkm,
    const bf16* __restrict__ Wvm,
    const float* __restrict__ bqv, const float* __restrict__ bkv,
    const float* __restrict__ bvv,
    const float* __restrict__ freqs,
    bf16* __restrict__ Qo, bf16* __restrict__ Ko, bf16* __restrict__ Vo)
{
    __shared__ __align__(16) bf16 smem[128 * 64 + 64 * 64];   // 24 KB
    bf16* As = smem;                 // [128][64]
    bf16* Bs = smem + 128 * 64;      // [64][64]

    const int which = blockIdx.x >> 9;            // 0=q 1=k 2=v (block-uniform)
    const int rem0  = blockIdx.x & 511;
    // XCD-chunked swizzle: xcd = bid&7 owns 64 tiles = 4 mb-rows x 16 nb.
    const int rem   = ((rem0 & 7) << 6) | (rem0 >> 3);
    const bf16* A    = which == 0 ? qa  : which == 1 ? ka  : va;
    const bf16* W    = which == 0 ? Wqm : which == 1 ? Wkm : Wvm;
    const float* bias = which == 0 ? bqv : which == 1 ? bkv : bvv;
    bf16* out        = which == 0 ? Qo  : which == 1 ? Ko  : Vo;

    const int mb = rem >> 4;     // 32 m-blocks
    const int nb = rem & 15;     // 16 n-blocks (one 64-wide head each)
    const int wave = threadIdx.x >> 6;
    const int lane = threadIdx.x & 63;
    const int col  = lane & 15;
    const int quad = lane >> 4;
    const int m0 = mb * 128, n0 = nb * 64;
    const int wm = wave * 32;    // 4 waves x 32 m-rows; all 64 n-cols per wave

    const int rr = lane >> 3;       // row within 8-row staging group
    const int c8 = lane & 7;        // linear source chunk (ascending lanes)
    const int cx = c8 ^ rr;         // XOR-permuted LDS slot

    f32x4 acc[2][4];
    #pragma unroll
    for (int i = 0; i < 2; ++i)
        #pragma unroll
        for (int j = 0; j < 4; ++j) acc[i][j] = (f32x4){0.f,0.f,0.f,0.f};

    bf16x8 sa0[4], sb0[2], sa1[4], sb1[2];
    // prologue: prefetch k=0 into s0 and k=64 into s1
    #pragma unroll
    for (int i = 0; i < 4; ++i) {
        int r = wave * 32 + i * 8 + rr;       // 0..127
        sa0[i] = ldb8(A + (size_t)(m0 + r) * DD + c8 * 8);
        sa1[i] = ldb8(A + (size_t)(m0 + r) * DD + 64 + c8 * 8);
    }
    #pragma unroll
    for (int i = 0; i < 2; ++i) {
        int r = wave * 16 + i * 8 + rr;       // 0..63
        sb0[i] = ldb8(W + (size_t)(n0 + r) * DD + c8 * 8);
        sb1[i] = ldb8(W + (size_t)(n0 + r) * DD + 64 + c8 * 8);
    }

    #pragma unroll 1
    for (int k0 = 0; k0 < DD; k0 += 128) {
        // ---- step A: consume s0 (tile k0), prefetch k0+128 into s0 ----
        __syncthreads();
        #pragma unroll
        for (int i = 0; i < 4; ++i) {
            int r = wave * 32 + i * 8 + rr;
            stb8(As + r * 64 + cx * 8, sa0[i]);
        }
        #pragma unroll
        for (int i = 0; i < 2; ++i) {
            int r = wave * 16 + i * 8 + rr;
            stb8(Bs + r * 64 + cx * 8, sb0[i]);
        }
        __syncthreads();
        if (k0 + 128 < DD) {
            #pragma unroll
            for (int i = 0; i < 4; ++i) {
                int r = wave * 32 + i * 8 + rr;
                sa0[i] = ldb8(A + (size_t)(m0 + r) * DD + k0 + 128 + c8 * 8);
            }
            #pragma unroll
            for (int i = 0; i < 2; ++i) {
                int r = wave * 16 + i * 8 + rr;
                sb0[i] = ldb8(W + (size_t)(n0 + r) * DD + k0 + 128 + c8 * 8);
            }
        }
        #pragma unroll
        for (int kk = 0; kk < 2; ++kk) {
            bf16x8 af[2], bfv[4];
            #pragma unroll
            for (int ms = 0; ms < 2; ++ms) {
                int R = wm + ms * 16 + col;
                af[ms] = ldb8(As + R * 64 + (((kk * 4 + quad) ^ (R & 7)) * 8));
            }
            #pragma unroll
            for (int ns = 0; ns < 4; ++ns) {
                int R = ns * 16 + col;
                bfv[ns] = ldb8(Bs + R * 64 + (((kk * 4 + quad) ^ (R & 7)) * 8));
            }
            #pragma unroll
            for (int ms = 0; ms < 2; ++ms)
                #pragma unroll
                for (int ns = 0; ns < 4; ++ns)
                    acc[ms][ns] = __builtin_amdgcn_mfma_f32_16x16x32_bf16(
                                      af[ms], bfv[ns], acc[ms][ns], 0, 0, 0);
        }

        // ---- step B: consume s1 (tile k0+64), prefetch k0+192 into s1 ----
        __syncthreads();
        #pragma unroll
        for (int i = 0; i < 4; ++i) {
            int r = wave * 32 + i * 8 + rr;
            stb8(As + r * 64 + cx * 8, sa1[i]);
        }
        #pragma unroll
        for (int i = 0; i < 2; ++i) {
            int r = wave * 16 + i * 8 + rr;
            stb8(Bs + r * 64 + cx * 8, sb1[i]);
        }
        __syncthreads();
        if (k0 + 192 < DD) {
            #pragma unroll
            for (int i = 0; i < 4; ++i) {
                int r = wave * 32 + i * 8 + rr;
                sa1[i] = ldb8(A + (size_t)(m0 + r) * DD + k0 + 192 + c8 * 8);
            }
            #pragma unroll
            for (int i = 0; i < 2; ++i) {
                int r = wave * 16 + i * 8 + rr;
                sb1[i] = ldb8(W + (size_t)(n0 + r) * DD + k0 + 192 + c8 * 8);
            }
        }
        #pragma unroll
        for (int kk = 0; kk < 2; ++kk) {
            bf16x8 af[2], bfv[4];
            #pragma unroll
            for (int ms = 0; ms < 2; ++ms) {
                int R = wm + ms * 16 + col;
                af[ms] = ldb8(As + R * 64 + (((kk * 4 + quad) ^ (R & 7)) * 8));
            }
            #pragma unroll
            for (int ns = 0; ns < 4; ++ns) {
                int R = ns * 16 + col;
                bfv[ns] = ldb8(Bs + R * 64 + (((kk * 4 + quad) ^ (R & 7)) * 8));
            }
            #pragma unroll
            for (int ms = 0; ms < 2; ++ms)
                #pragma unroll
                for (int ns = 0; ns < 4; ++ns)
                    acc[ms][ns] = __builtin_amdgcn_mfma_f32_16x16x32_bf16(
                                      af[ms], bfv[ns], acc[ms][ns], 0, 0, 0);
        }
    }

    float bi[4];
    #pragma unroll
    for (int ns = 0; ns < 4; ++ns) bi[ns] = bias[n0 + ns * 16 + col];

    const int b  = m0 >> 11;          // block spans a single batch (2048%128==0)
    const int lb = m0 & (LL - 1);
    const int head = nb;

    __syncthreads();   // all waves done with As/Bs reads before tile reuse

    if (which != 2) {
        // ---- stage RoPE'd 128(l) x 64(d = 1 head) tile into LDS ----
        #pragma unroll
        for (int ms = 0; ms < 2; ++ms) {
            #pragma unroll
            for (int reg = 0; reg < 4; ++reg) {
                int r = wm + ms * 16 + quad * 4 + reg;   // local l-row
                int l = lb + r;
                float v0 = acc[ms][0][reg] + bi[0];
                float v1 = acc[ms][1][reg] + bi[1];
                float v2 = acc[ms][2][reg] + bi[2];
                float v3 = acc[ms][3][reg] + bi[3];
                float a0 = freqs[l * HDIM + col];
                float a1 = freqs[l * HDIM + 16 + col];
                float c0 = cosf(a0), s0 = sinf(a0);
                float c1 = cosf(a1), s1 = sinf(a1);
                float o0 = v0 * c0 - v2 * s0;     // d<32: x*cos - x[d+32]*sin
                float o2 = v2 * c0 + v0 * s0;     // d>=32: x*cos + x[d-32]*sin
                float o1 = v1 * c1 - v3 * s1;
                float o3 = v3 * c1 + v1 * s1;
                int sw = (r & 7) << 3;            // XOR on 8-elem chunks
                smem[r * 64 + ((col +  0) ^ sw)] = __float2bfloat16(o0);
                smem[r * 64 + ((col + 16) ^ sw)] = __float2bfloat16(o1);
                smem[r * 64 + ((col + 32) ^ sw)] = __float2bfloat16(o2);
                smem[r * 64 + ((col + 48) ^ sw)] = __float2bfloat16(o3);
            }
        }
        __syncthreads();
        // ---- write out: 1 KB contiguous per instruction ----
        #pragma unroll
        for (int j = 0; j < 4; ++j) {
            int row = wave * 32 + j * 8 + (lane >> 3);
            int d7  = (lane & 7) * 8;
            bf16x8 vv = ldb8(smem + row * 64 + (d7 ^ ((row & 7) << 3)));
            stb8(out + (((size_t)(b * HH + head)) * LL + lb + row) * HDIM + d7, vv);
        }
    } else {
        // ---- V^T: stage as 64(d) x 128(l), XOR on 8-elem l-chunks using
        // 2 row bits (writes are 4-elem aligned, reads 8-elem aligned) ----
        #pragma unroll
        for (int ms = 0; ms < 2; ++ms) {
            int lb4 = wm + ms * 16 + quad * 4;
            #pragma unroll
            for (int ns = 0; ns < 4; ++ns) {
                bf16x4 pk;
                #pragma unroll
                for (int reg = 0; reg < 4; ++reg)
                    pk[reg] = f2b(acc[ms][ns][reg] + bi[ns]);
                int dl  = ns * 16 + col;               // d-row 0..63
                int lsw = lb4 ^ ((dl & 3) << 3);       // flips bits 3..4 only
                *(bf16x4*)(void*)(smem + dl * 128 + lsw) = pk;
            }
        }
        __syncthreads();
        // ---- write out: 4 d-rows x 256B contiguous runs per instruction ----
        #pragma unroll
        for (int j = 0; j < 4; ++j) {
            int row = wave * 16 + j * 4 + (lane >> 4);  // d-row 0..63
            int c16 = lane & 15;
            bf16x8 vv = ldb8(smem + row * 128 + ((c16 * 8) ^ ((row & 3) << 3)));
            stb8(out + ((size_t)(b * HH + head) * HDIM + row) * LL + lb + c16 * 8,
                 vv);
        }
    }
}

// ---------------------------------------------------------------------------
// Flash attention — r19 version verbatim (64-q-row blocks, 4 blocks/CU).
// ---------------------------------------------------------------------------
__global__ __launch_bounds__(256, 4) void attn_mfma(
    const bf16* __restrict__ Q,   // [B*H, L, HD]
    const bf16* __restrict__ K,   // [B*H, L, HD]
    const bf16* __restrict__ VT,  // [B*H, HD, L]
    bf16* __restrict__ O)         // [B, L, D]
{
    __shared__ __align__(16) bf16 smem[64 * 64 + 64 * 64 + 4 * 16 * PSTR];
    bf16* Ks  = smem;                  // [64][64]  8 KB
    bf16* Vs  = smem + 64 * 64;        // [64][64]  8 KB
    bf16* Pb  = smem + 2 * 64 * 64;    // P buffer: 64 rows x PSTR = 9.2 KB
    bf16* Ost = smem;                  // epilogue: [64][64] = 8 KB (= Ks)

    const int wave = threadIdx.x >> 6;   // 0..3
    const int lane = threadIdx.x & 63;
    const int col  = lane & 15;
    const int quad = lane >> 4;
    // XCD-chunked swizzle over 1024 blocks: xcd = bid&7 owns 128 consecutive
    // tiles (= 4 consecutive bh values x 32 q-blocks).
    const int tile = ((blockIdx.x & 7) << 7) | (blockIdx.x >> 3);
    const int bh   = tile >> 5;
    const int qblk = tile & 31;
    const int q0   = qblk * 64 + wave * 16;

    const bf16* Kg = K  + (size_t)bh * LL * HDIM;
    const bf16* Vg = VT + (size_t)bh * HDIM * LL;
    const bf16* Qh = Q  + ((size_t)bh * LL + q0) * HDIM;

    const int rr = lane >> 3;
    const int c8 = lane & 7;
    const int cx = c8 ^ rr;

    bf16x8 qf[2];
    #pragma unroll
    for (int hh = 0; hh < 2; ++hh)
        qf[hh] = ldb8(Qh + (size_t)col * HDIM + hh * 32 + quad * 8);

    bf16x8 ones;
    #pragma unroll
    for (int j = 0; j < 8; ++j) ones[j] = f2b(1.0f);

    f32x4 oacc[4], lacc;
    lacc = (f32x4){0.f,0.f,0.f,0.f};
    #pragma unroll
    for (int n = 0; n < 4; ++n) oacc[n] = (f32x4){0.f,0.f,0.f,0.f};

    bf16x8 sk[2], sv[2];
    #pragma unroll
    for (int i = 0; i < 2; ++i) {
        int r = i * 32 + wave * 8 + rr;
        sk[i] = ldb8(Kg + (size_t)r * HDIM + c8 * 8);
        sv[i] = ldb8(Vg + (size_t)r * LL + c8 * 8);
    }

    for (int kv0 = 0; kv0 < LL; kv0 += 64) {
        __syncthreads();
        #pragma unroll
        for (int i = 0; i < 2; ++i) {
            int r = i * 32 + wave * 8 + rr;
            stb8(Ks + r * 64 + cx * 8, sk[i]);
            stb8(Vs + r * 64 + cx * 8, sv[i]);
        }
        __syncthreads();
        if (kv0 + 64 < LL) {
            #pragma unroll
            for (int i = 0; i < 2; ++i) {
                int r = i * 32 + wave * 8 + rr;
                sk[i] = ldb8(Kg + (size_t)(kv0 + 64 + r) * HDIM + c8 * 8);
                sv[i] = ldb8(Vg + (size_t)r * LL + kv0 + 64 + c8 * 8);
            }
        }

        bf16x8 kf[8];
        #pragma unroll
        for (int t = 0; t < 4; ++t) {
            int rk = t * 16 + col;
            #pragma unroll
            for (int hh = 0; hh < 2; ++hh) {
                int csw = (hh * 4 + quad) ^ (rk & 7);
                kf[t * 2 + hh] = ldb8(Ks + rk * 64 + csw * 8);
            }
        }
        #pragma unroll
        for (int t = 0; t < 4; ++t) {
            f32x4 s = {0.f,0.f,0.f,0.f};
            s = __builtin_amdgcn_mfma_f32_16x16x32_bf16(kf[2*t],   qf[0], s, 0, 0, 0);
            s = __builtin_amdgcn_mfma_f32_16x16x32_bf16(kf[2*t+1], qf[1], s, 0, 0, 0);
            bf16x4 p4;
            #pragma unroll
            for (int r = 0; r < 4; ++r) p4[r] = f2b(__expf(s[r] * 0.125f));
            *(bf16x4*)(void*)(Pb + ((size_t)(wave * 16 + col)) * PSTR
                                 + t * 16 + quad * 4) = p4;
        }
        bf16x8 vf[8];
        #pragma unroll
        for (int n = 0; n < 4; ++n) {
            int rv = n * 16 + col;
            #pragma unroll
            for (int ks = 0; ks < 2; ++ks) {
                int csw = (ks * 4 + quad) ^ (rv & 7);
                vf[n * 2 + ks] = ldb8(Vs + rv * 64 + csw * 8);
            }
        }
        #pragma unroll
        for (int ks = 0; ks < 2; ++ks) {
            bf16x8 pa = ldb8(Pb + ((size_t)(wave * 16 + col)) * PSTR
                                + ks * 32 + quad * 8);
            lacc = __builtin_amdgcn_mfma_f32_16x16x32_bf16(pa, ones, lacc, 0, 0, 0);
            #pragma unroll
            for (int n = 0; n < 4; ++n)
                oacc[n] = __builtin_amdgcn_mfma_f32_16x16x32_bf16(
                              pa, vf[n * 2 + ks], oacc[n], 0, 0, 0);
        }
    }

    const int b = bh >> 4, h = bh & 15;

    __syncthreads();   // done with Ks/Vs/Pb before reuse as Ost
    #pragma unroll
    for (int reg = 0; reg < 4; ++reg) {
        float inv = 1.f / lacc[reg];
        int r  = wave * 16 + quad * 4 + reg;   // local l-row 0..63
        int sw = (r & 7) << 3;
        Ost[r * 64 + ((col +  0) ^ sw)] = __float2bfloat16(oacc[0][reg] * inv);
        Ost[r * 64 + ((col + 16) ^ sw)] = __float2bfloat16(oacc[1][reg] * inv);
        Ost[r * 64 + ((col + 32) ^ sw)] = __float2bfloat16(oacc[2][reg] * inv);
        Ost[r * 64 + ((col + 48) ^ sw)] = __float2bfloat16(oacc[3][reg] * inv);
    }
    __syncthreads();
    #pragma unroll
    for (int j = 0; j < 2; ++j) {
        int row = wave * 16 + j * 8 + (lane >> 3);    // 0..63
        int d7  = (lane & 7) * 8;
        bf16x8 vv = ldb8(Ost + row * 64 + (d7 ^ ((row & 7) << 3)));
        int l = qblk * 64 + row;
        stb8(O + ((size_t)b * LL + l) * DD + h * HDIM + d7, vv);
    }
}

// ---------------------------------------------------------------------------
// Output projection — r19 version verbatim (64x64 tiles, 4 blocks/CU).
// ---------------------------------------------------------------------------
__global__ __launch_bounds__(256, 4) void out_gemm(
    const bf16* __restrict__ Ain,   // [B*L, D] bf16
    const bf16* __restrict__ W,     // [D, D] bf16
    const float* __restrict__ bias, // [D] f32
    float* __restrict__ out)        // [B*L, D] f32
{
    __shared__ __align__(16) bf16 smem[8192];    // 16 KB
    bf16* As = smem;                 // [64][64] 8 KB
    bf16* Bs = smem + 64 * 64;       // [64][64] 8 KB
    float* St = (float*)(void*)smem; // epilogue: [64][64] f32 = 16 KB

    const int tid = threadIdx.x;
    // XCD-chunked swizzle over 1024 blocks: xcd owns 128 tiles = 8mb x 16nb.
    const int tile = ((blockIdx.x & 7) << 7) | (blockIdx.x >> 3);
    const int mb = tile >> 4;           // 64 m-blocks
    const int nb = tile & 15;           // 16 n-blocks
    const int wave = tid >> 6;          // 0..3
    const int lane = tid & 63;
    const int col  = lane & 15;
    const int quad = lane >> 4;
    const int m0 = mb * 64, n0 = nb * 64;
    const int wm = (wave & 1) * 32;     // 2 m-halves
    const int wn = (wave >> 1) * 32;    // 2 n-halves

    const int rr = lane >> 3;
    const int c8 = lane & 7;
    const int cx = c8 ^ rr;

    f32x4 acc[2][2];
    #pragma unroll
    for (int i = 0; i < 2; ++i)
        #pragma unroll
        for (int j = 0; j < 2; ++j) acc[i][j] = (f32x4){0.f,0.f,0.f,0.f};

    bf16x8 sa[2], sb[2];
    #pragma unroll
    for (int i = 0; i < 2; ++i) {
        int r = (i * 4 + wave) * 8 + rr;   // 0..63
        sa[i] = ldb8(Ain + (size_t)(m0 + r) * DD + c8 * 8);
        sb[i] = ldb8(W + (size_t)(n0 + r) * DD + c8 * 8);
    }

    for (int k0 = 0; k0 < DD; k0 += 64) {
        __syncthreads();
        #pragma unroll
        for (int i = 0; i < 2; ++i) {
            int r = (i * 4 + wave) * 8 + rr;
            stb8(As + r * 64 + cx * 8, sa[i]);
            stb8(Bs + r * 64 + cx * 8, sb[i]);
        }
        __syncthreads();
        if (k0 + 64 < DD) {
            #pragma unroll
            for (int i = 0; i < 2; ++i) {
                int r = (i * 4 + wave) * 8 + rr;
                sa[i] = ldb8(Ain + (size_t)(m0 + r) * DD + k0 + 64 + c8 * 8);
                sb[i] = ldb8(W + (size_t)(n0 + r) * DD + k0 + 64 + c8 * 8);
            }
        }

        #pragma unroll
        for (int kk = 0; kk < 2; ++kk) {
            bf16x8 af[2], bfv[2];
            #pragma unroll
            for (int ms = 0; ms < 2; ++ms) {
                int R = wm + ms * 16 + col;
                af[ms] = ldb8(As + R * 64 + (((kk * 4 + quad) ^ (R & 7)) * 8));
            }
            #pragma unroll
            for (int ns = 0; ns < 2; ++ns) {
                int R = wn + ns * 16 + col;
                bfv[ns] = ldb8(Bs + R * 64 + (((kk * 4 + quad) ^ (R & 7)) * 8));
            }
            #pragma unroll
            for (int ms = 0; ms < 2; ++ms)
                #pragma unroll
                for (int ns = 0; ns < 2; ++ns)
                    acc[ms][ns] = __builtin_amdgcn_mfma_f32_16x16x32_bf16(
                                      af[ms], bfv[ns], acc[ms][ns], 0, 0, 0);
        }
    }

    float bi[2];
    #pragma unroll
    for (int ns = 0; ns < 2; ++ns) bi[ns] = bias[n0 + wn + ns * 16 + col];

    __syncthreads();   // done with As/Bs before St reuse
    #pragma unroll
    for (int ms = 0; ms < 2; ++ms) {
        #pragma unroll
        for (int reg = 0; reg < 4; ++reg) {
            int r  = wm + ms * 16 + quad * 4 + reg;   // local m-row 0..63
            int sw = (r & 3) << 2;                    // XOR on 4-elem f32 chunks
            St[r * 64 + ((wn + col +  0) ^ sw)] = acc[ms][0][reg] + bi[0];
            St[r * 64 + ((wn + col + 16) ^ sw)] = acc[ms][1][reg] + bi[1];
        }
    }
    __syncthreads();
    #pragma unroll
    for (int j = 0; j < 4; ++j) {
        int row = j * 16 + (tid >> 4);                // 0..63
        int c4  = (tid & 15) * 4;
        float4 vv = *(const float4*)(const void*)(St + row * 64 + (c4 ^ ((row & 3) << 2)));
        *(float4*)(void*)(out + (size_t)(m0 + row) * DD + n0 + c4) = vv;
    }
}

extern "C" void kernel_launch(void* const* d_in, const int* in_sizes, int n_in,
                              void* d_out, int out_size, void* d_ws, size_t ws_size,
                              hipStream_t stream) {
    const float* q     = (const float*)d_in[0];
    const float* k     = (const float*)d_in[1];
    const float* v     = (const float*)d_in[2];
    const float* freqs = (const float*)d_in[3];
    const float* Wq = (const float*)d_in[4];
    const float* bq = (const float*)d_in[5];
    const float* Wk = (const float*)d_in[6];
    const float* bk = (const float*)d_in[7];
    const float* Wv = (const float*)d_in[8];
    const float* bv = (const float*)d_in[9];
    const float* Wo = (const float*)d_in[10];
    const float* bo = (const float*)d_in[11];
    float* out = (float*)d_out;

    const size_t welems = (size_t)DD * DD;             // 1M
    const size_t elems  = (size_t)BB * HH * LL * HDIM; // 4M (= B*L*D)
    bf16* Wqb = (bf16*)d_ws;
    bf16* Wkb = Wqb + welems;
    bf16* Wvb = Wkb + welems;
    bf16* Wob = Wvb + welems;
    bf16* qb  = Wob + welems;
    bf16* kb  = qb + elems;
    bf16* vb  = kb + elems;
    bf16* Qr  = vb + elems;
    bf16* Kr  = Qr + elems;
    bf16* Vt  = Kr + elems;   // V^T [B*H, HD, L]
    bf16* Obf = Vt + elems;   // O [B, L, D]; total ws: 8 + 24 + 32 = 64 MB

    cvt_all<<<dim3(16384), dim3(256), 0, stream>>>(Wq, Wk, Wv, Wo, q, k, v,
                                                   Wqb, Wkb, Wvb, Wob, qb, kb, vb);
    qkv3_gemm<<<dim3(1536), dim3(256), 0, stream>>>(qb, kb, vb, Wqb, Wkb, Wvb,
                                                    bq, bk, bv, freqs, Qr, Kr, Vt);
    attn_mfma<<<dim3(BB * HH * (LL / 64)), dim3(256), 0, stream>>>(Qr, Kr, Vt, Obf);
    out_gemm<<<dim3(1024), dim3(256), 0, stream>>>(Obf, Wob, bo, out);
}

// Round 13
// 225.560 us; speedup vs baseline: 1.7811x; 1.7811x over previous
//
#include <hip/hip_runtime.h>
#include <hip/hip_bf16.h>

// Problem constants (B=2, L=2048, D=1024, H=16, HD=64)
#define BB 2
#define LL 2048
#define DD 1024
#define HH 16
#define HDIM 64
#define PSTR 72   // padded P-buffer row stride (elems)

typedef __hip_bfloat16 bf16;
typedef __attribute__((ext_vector_type(8))) __bf16 bf16x8;     // MFMA A/B frag
typedef __attribute__((ext_vector_type(4))) __bf16 bf16x4;     // 8B packed store
typedef __attribute__((ext_vector_type(4))) float f32x4;       // MFMA C/D frag

__device__ inline __bf16 f2b(float f) {
    __hip_bfloat16 h = __float2bfloat16(f);
    return __builtin_bit_cast(__bf16, h);
}
__device__ inline bf16x8 ldb8(const bf16* p) {
    return *(const bf16x8*)(const void*)p;
}
__device__ inline void stb8(bf16* p, bf16x8 v) {
    *(bf16x8*)(void*)p = v;
}

// ---------------------------------------------------------------------------
// Fused f32 -> bf16 convert (streaming) — unchanged.
// ---------------------------------------------------------------------------
__global__ __launch_bounds__(256) void cvt_all(
    const float* __restrict__ w0, const float* __restrict__ w1,
    const float* __restrict__ w2, const float* __restrict__ w3,
    const float* __restrict__ a0, const float* __restrict__ a1,
    const float* __restrict__ a2,
    bf16* __restrict__ ow0, bf16* __restrict__ ow1,
    bf16* __restrict__ ow2, bf16* __restrict__ ow3,
    bf16* __restrict__ oa0, bf16* __restrict__ oa1, bf16* __restrict__ oa2)
{
    const float* in;
    bf16* out;
    int i;
    if (blockIdx.x < 4096) {
        int seg = blockIdx.x >> 10;
        i = ((blockIdx.x & 1023) * 256 + threadIdx.x) * 4;
        in  = seg == 0 ? w0 : seg == 1 ? w1 : seg == 2 ? w2 : w3;
        out = seg == 0 ? ow0 : seg == 1 ? ow1 : seg == 2 ? ow2 : ow3;
    } else {
        int bb = blockIdx.x - 4096;
        int seg = bb >> 12;
        i = ((bb & 4095) * 256 + threadIdx.x) * 4;
        in  = seg == 0 ? a0 : seg == 1 ? a1 : a2;
        out = seg == 0 ? oa0 : seg == 1 ? oa1 : oa2;
    }
    float4 f = *(const float4*)(const void*)(in + i);
    bf16x4 o;
    o[0] = f2b(f.x);
    o[1] = f2b(f.y);
    o[2] = f2b(f.z);
    o[3] = f2b(f.w);
    *(bf16x4*)(void*)(out + i) = o;
}

// ---------------------------------------------------------------------------
// Fused Q/K/V projection. ROUND-21: 64x64 tile, (256,8) -> up to 8 blocks/CU
// (wave-capped), continuing the confirmed TLP lever (3->6 blocks/CU was
// 142->98us). r20's depth-2 prefetch REVERTED (VGPR 48-over the (256,6) cap
// -> scratch spill, +670MB traffic, 216us). Register budget verified this
// time: acc[1][4]=16 + sa/sb=16 + temps < the 64-VGPR cap of (256,8).
// Grid 3072 = 3 ops x 64mb x 16nb; XCD swizzle: xcd owns 128 tiles
// (8 mb-rows x 16 nb -> 1MB A + 2MB W per XCD L2).
// ---------------------------------------------------------------------------
__global__ __launch_bounds__(256, 8) void qkv3_gemm(
    const bf16* __restrict__ qa, const bf16* __restrict__ ka,
    const bf16* __restrict__ va,
    const bf16* __restrict__ Wqm, const bf16* __restrict__ Wkm,
    const bf16* __restrict__ Wvm,
    const float* __restrict__ bqv, const float* __restrict__ bkv,
    const float* __restrict__ bvv,
    const float* __restrict__ freqs,
    bf16* __restrict__ Qo, bf16* __restrict__ Ko, bf16* __restrict__ Vo)
{
    __shared__ __align__(16) bf16 smem[64 * 64 + 64 * 64];   // 16 KB
    bf16* As = smem;                 // [64][64]
    bf16* Bs = smem + 64 * 64;       // [64][64]

    const int which = blockIdx.x >> 10;           // 0=q 1=k 2=v (block-uniform)
    const int rem0  = blockIdx.x & 1023;
    // XCD-chunked swizzle: xcd = bid&7 owns 128 tiles = 8 mb-rows x 16 nb.
    const int rem   = ((rem0 & 7) << 7) | (rem0 >> 3);
    const bf16* A    = which == 0 ? qa  : which == 1 ? ka  : va;
    const bf16* W    = which == 0 ? Wqm : which == 1 ? Wkm : Wvm;
    const float* bias = which == 0 ? bqv : which == 1 ? bkv : bvv;
    bf16* out        = which == 0 ? Qo  : which == 1 ? Ko  : Vo;

    const int mb = rem >> 4;     // 64 m-blocks
    const int nb = rem & 15;     // 16 n-blocks (one 64-wide head each)
    const int wave = threadIdx.x >> 6;
    const int lane = threadIdx.x & 63;
    const int col  = lane & 15;
    const int quad = lane >> 4;
    const int m0 = mb * 64, n0 = nb * 64;
    const int wm = wave * 16;    // 4 waves x 16 m-rows; all 64 n-cols per wave

    const int rr = lane >> 3;       // row within 8-row staging group
    const int c8 = lane & 7;        // linear source chunk (ascending lanes)
    const int cx = c8 ^ rr;         // XOR-permuted LDS slot

    f32x4 acc[4];
    #pragma unroll
    for (int j = 0; j < 4; ++j) acc[j] = (f32x4){0.f,0.f,0.f,0.f};

    bf16x8 sa[2], sb[2];
    #pragma unroll
    for (int i = 0; i < 2; ++i) {
        int r = wave * 16 + i * 8 + rr;       // 0..63
        sa[i] = ldb8(A + (size_t)(m0 + r) * DD + c8 * 8);
        sb[i] = ldb8(W + (size_t)(n0 + r) * DD + c8 * 8);
    }

    for (int k0 = 0; k0 < DD; k0 += 64) {
        __syncthreads();
        #pragma unroll
        for (int i = 0; i < 2; ++i) {
            int r = wave * 16 + i * 8 + rr;
            stb8(As + r * 64 + cx * 8, sa[i]);
            stb8(Bs + r * 64 + cx * 8, sb[i]);
        }
        __syncthreads();
        if (k0 + 64 < DD) {
            #pragma unroll
            for (int i = 0; i < 2; ++i) {
                int r = wave * 16 + i * 8 + rr;
                sa[i] = ldb8(A + (size_t)(m0 + r) * DD + k0 + 64 + c8 * 8);
                sb[i] = ldb8(W + (size_t)(n0 + r) * DD + k0 + 64 + c8 * 8);
            }
        }

        #pragma unroll
        for (int kk = 0; kk < 2; ++kk) {
            bf16x8 af, bfv[4];
            {
                int R = wm + col;
                af = ldb8(As + R * 64 + (((kk * 4 + quad) ^ (R & 7)) * 8));
            }
            #pragma unroll
            for (int ns = 0; ns < 4; ++ns) {
                int R = ns * 16 + col;
                bfv[ns] = ldb8(Bs + R * 64 + (((kk * 4 + quad) ^ (R & 7)) * 8));
            }
            #pragma unroll
            for (int ns = 0; ns < 4; ++ns)
                acc[ns] = __builtin_amdgcn_mfma_f32_16x16x32_bf16(
                              af, bfv[ns], acc[ns], 0, 0, 0);
        }
    }

    float bi[4];
    #pragma unroll
    for (int ns = 0; ns < 4; ++ns) bi[ns] = bias[n0 + ns * 16 + col];

    const int b  = m0 >> 11;          // block spans a single batch (2048%64==0)
    const int lb = m0 & (LL - 1);
    const int head = nb;

    __syncthreads();   // all waves done with As/Bs reads before tile reuse

    if (which != 2) {
        // ---- stage RoPE'd 64(l) x 64(d = 1 head) tile into LDS ----
        #pragma unroll
        for (int reg = 0; reg < 4; ++reg) {
            int r = wm + quad * 4 + reg;   // local l-row 0..63
            int l = lb + r;
            float v0 = acc[0][reg] + bi[0];
            float v1 = acc[1][reg] + bi[1];
            float v2 = acc[2][reg] + bi[2];
            float v3 = acc[3][reg] + bi[3];
            float a0 = freqs[l * HDIM + col];
            float a1 = freqs[l * HDIM + 16 + col];
            float c0 = cosf(a0), s0 = sinf(a0);
            float c1 = cosf(a1), s1 = sinf(a1);
            float o0 = v0 * c0 - v2 * s0;     // d<32: x*cos - x[d+32]*sin
            float o2 = v2 * c0 + v0 * s0;     // d>=32: x*cos + x[d-32]*sin
            float o1 = v1 * c1 - v3 * s1;
            float o3 = v3 * c1 + v1 * s1;
            int sw = (r & 7) << 3;            // XOR on 8-elem chunks
            smem[r * 64 + ((col +  0) ^ sw)] = __float2bfloat16(o0);
            smem[r * 64 + ((col + 16) ^ sw)] = __float2bfloat16(o1);
            smem[r * 64 + ((col + 32) ^ sw)] = __float2bfloat16(o2);
            smem[r * 64 + ((col + 48) ^ sw)] = __float2bfloat16(o3);
        }
        __syncthreads();
        // ---- write out: 1 KB contiguous per instruction ----
        #pragma unroll
        for (int j = 0; j < 2; ++j) {
            int row = wave * 16 + j * 8 + (lane >> 3);   // 0..63
            int d7  = (lane & 7) * 8;
            bf16x8 vv = ldb8(smem + row * 64 + (d7 ^ ((row & 7) << 3)));
            stb8(out + (((size_t)(b * HH + head)) * LL + lb + row) * HDIM + d7, vv);
        }
    } else {
        // ---- V^T: stage as 64(d) x 64(l), XOR on l bits 3..4 ----
        {
            int lb4 = wm + quad * 4;             // l-offset 0..63 (4-aligned)
            #pragma unroll
            for (int ns = 0; ns < 4; ++ns) {
                bf16x4 pk;
                #pragma unroll
                for (int reg = 0; reg < 4; ++reg)
                    pk[reg] = f2b(acc[ns][reg] + bi[ns]);
                int dl  = ns * 16 + col;               // d-row 0..63
                int lsw = lb4 ^ ((dl & 3) << 3);       // flips bits 3..4 only
                *(bf16x4*)(void*)(smem + dl * 64 + lsw) = pk;
            }
        }
        __syncthreads();
        // ---- write out: 8 d-rows x 128B contiguous runs per instruction ----
        #pragma unroll
        for (int j = 0; j < 2; ++j) {
            int row = wave * 16 + j * 8 + (lane >> 3);  // d-row 0..63
            int c8w = lane & 7;
            bf16x8 vv = ldb8(smem + row * 64 + ((c8w * 8) ^ ((row & 3) << 3)));
            stb8(out + ((size_t)(b * HH + head) * HDIM + row) * LL + lb + c8w * 8,
                 vv);
        }
    }
}

// ---------------------------------------------------------------------------
// Flash attention — r16 version verbatim (256 q-rows, 8 waves; part of the
// measured-best 279us configuration; r19's 4-blocks/CU variant was neutral).
// ---------------------------------------------------------------------------
__global__ __launch_bounds__(512, 2) void attn_mfma(
    const bf16* __restrict__ Q,   // [B*H, L, HD]
    const bf16* __restrict__ K,   // [B*H, L, HD]
    const bf16* __restrict__ VT,  // [B*H, HD, L]
    bf16* __restrict__ O)         // [B, L, D]
{
    __shared__ __align__(16) bf16 smem[64 * 64 + 64 * 64 + 8 * 2 * 16 * PSTR];
    bf16* Ks  = smem;                  // [64][64]  8 KB
    bf16* Vs  = smem + 64 * 64;        // [64][64]  8 KB
    bf16* Pb  = smem + 2 * 64 * 64;    // P buffer  36 KB
    bf16* Ost = smem;                  // epilogue: [256][64] = 32 KB

    const int tid  = threadIdx.x;
    const int wave = tid >> 6;    // 0..7
    const int lane = tid & 63;
    const int col  = lane & 15;
    const int quad = lane >> 4;
    // XCD-chunked swizzle over 256 blocks: xcd = bid&7 owns 32 consecutive
    // tiles (= 4 consecutive bh values x 8 q-blocks).
    const int tile = ((blockIdx.x & 7) << 5) | (blockIdx.x >> 3);
    const int bh   = tile >> 3;
    const int qblk = tile & 7;
    const int q0   = qblk * 256 + wave * 32;

    const bf16* Kg = K  + (size_t)bh * LL * HDIM;
    const bf16* Vg = VT + (size_t)bh * HDIM * LL;
    const bf16* Qh = Q  + ((size_t)bh * LL + q0) * HDIM;

    const int rr = lane >> 3;
    const int c8 = lane & 7;
    const int cx = c8 ^ rr;

    bf16x8 qf[2][2];
    #pragma unroll
    for (int u = 0; u < 2; ++u)
        #pragma unroll
        for (int hh = 0; hh < 2; ++hh)
            qf[u][hh] = ldb8(Qh + (size_t)(u * 16 + col) * HDIM + hh * 32 + quad * 8);

    bf16x8 ones;
    #pragma unroll
    for (int j = 0; j < 8; ++j) ones[j] = f2b(1.0f);

    f32x4 oacc[2][4], lacc[2];
    #pragma unroll
    for (int u = 0; u < 2; ++u) {
        lacc[u] = (f32x4){0.f,0.f,0.f,0.f};
        #pragma unroll
        for (int n = 0; n < 4; ++n) oacc[u][n] = (f32x4){0.f,0.f,0.f,0.f};
    }

    bf16x8 sk, sv;
    {
        int r = wave * 8 + rr;                 // 0..63
        sk = ldb8(Kg + (size_t)r * HDIM + c8 * 8);
        sv = ldb8(Vg + (size_t)r * LL + c8 * 8);
    }

    for (int kv0 = 0; kv0 < LL; kv0 += 64) {
        __syncthreads();
        {
            int r = wave * 8 + rr;
            stb8(Ks + r * 64 + cx * 8, sk);
            stb8(Vs + r * 64 + cx * 8, sv);
        }
        __syncthreads();
        if (kv0 + 64 < LL) {
            int r = wave * 8 + rr;
            sk = ldb8(Kg + (size_t)(kv0 + 64 + r) * HDIM + c8 * 8);
            sv = ldb8(Vg + (size_t)r * LL + kv0 + 64 + c8 * 8);
        }

        bf16x8 kf[8];
        #pragma unroll
        for (int t = 0; t < 4; ++t) {
            int rk = t * 16 + col;
            #pragma unroll
            for (int hh = 0; hh < 2; ++hh) {
                int csw = (hh * 4 + quad) ^ (rk & 7);
                kf[t * 2 + hh] = ldb8(Ks + rk * 64 + csw * 8);
            }
        }
        #pragma unroll
        for (int u = 0; u < 2; ++u) {
            #pragma unroll
            for (int t = 0; t < 4; ++t) {
                f32x4 s = {0.f,0.f,0.f,0.f};
                s = __builtin_amdgcn_mfma_f32_16x16x32_bf16(kf[2*t],   qf[u][0], s, 0, 0, 0);
                s = __builtin_amdgcn_mfma_f32_16x16x32_bf16(kf[2*t+1], qf[u][1], s, 0, 0, 0);
                bf16x4 p4;
                #pragma unroll
                for (int r = 0; r < 4; ++r) p4[r] = f2b(__expf(s[r] * 0.125f));
                *(bf16x4*)(void*)(Pb + ((size_t)(wave * 2 + u) * 16 + col) * PSTR
                                     + t * 16 + quad * 4) = p4;
            }
        }
        bf16x8 vf[8];
        #pragma unroll
        for (int n = 0; n < 4; ++n) {
            int rv = n * 16 + col;
            #pragma unroll
            for (int ks = 0; ks < 2; ++ks) {
                int csw = (ks * 4 + quad) ^ (rv & 7);
                vf[n * 2 + ks] = ldb8(Vs + rv * 64 + csw * 8);
            }
        }
        #pragma unroll
        for (int u = 0; u < 2; ++u) {
            #pragma unroll
            for (int ks = 0; ks < 2; ++ks) {
                bf16x8 pa = ldb8(Pb + ((size_t)(wave * 2 + u) * 16 + col) * PSTR
                                    + ks * 32 + quad * 8);
                lacc[u] = __builtin_amdgcn_mfma_f32_16x16x32_bf16(pa, ones, lacc[u], 0, 0, 0);
                #pragma unroll
                for (int n = 0; n < 4; ++n)
                    oacc[u][n] = __builtin_amdgcn_mfma_f32_16x16x32_bf16(
                                     pa, vf[n * 2 + ks], oacc[u][n], 0, 0, 0);
            }
        }
    }

    const int b = bh >> 4, h = bh & 15;

    __syncthreads();   // done with Ks/Vs/Pb before reuse as Ost
    #pragma unroll
    for (int u = 0; u < 2; ++u) {
        #pragma unroll
        for (int reg = 0; reg < 4; ++reg) {
            float inv = 1.f / lacc[u][reg];
            int r  = wave * 32 + u * 16 + quad * 4 + reg;   // local l-row 0..255
            int sw = (r & 7) << 3;
            Ost[r * 64 + ((col +  0) ^ sw)] = __float2bfloat16(oacc[u][0][reg] * inv);
            Ost[r * 64 + ((col + 16) ^ sw)] = __float2bfloat16(oacc[u][1][reg] * inv);
            Ost[r * 64 + ((col + 32) ^ sw)] = __float2bfloat16(oacc[u][2][reg] * inv);
            Ost[r * 64 + ((col + 48) ^ sw)] = __float2bfloat16(oacc[u][3][reg] * inv);
        }
    }
    __syncthreads();
    #pragma unroll
    for (int j = 0; j < 4; ++j) {
        int row = wave * 32 + j * 8 + (lane >> 3);    // 0..255
        int d7  = (lane & 7) * 8;
        bf16x8 vv = ldb8(Ost + row * 64 + (d7 ^ ((row & 7) << 3)));
        int l = qblk * 256 + row;
        stb8(O + ((size_t)b * LL + l) * DD + h * HDIM + d7, vv);
    }
}

// ---------------------------------------------------------------------------
// Output projection — r16 version verbatim (128x128, 512 thr; part of the
// measured-best 279us configuration).
// ---------------------------------------------------------------------------
__global__ __launch_bounds__(512, 1) void out_gemm(
    const bf16* __restrict__ Ain,   // [B*L, D] bf16
    const bf16* __restrict__ W,     // [D, D] bf16
    const float* __restrict__ bias, // [D] f32
    float* __restrict__ out)        // [B*L, D] f32
{
    __shared__ __align__(16) bf16 smem[32768];   // 64 KB
    bf16* As = smem;                 // [128][64] 16 KB
    bf16* Bs = smem + 128 * 64;      // [128][64] 16 KB
    float* St = (float*)(void*)smem; // epilogue: [128][128] f32 = 64 KB

    const int tid = threadIdx.x;
    // XCD-chunked swizzle over 256 blocks: xcd owns 32 tiles = 4mb x 8nb.
    const int tile = ((blockIdx.x & 7) << 5) | (blockIdx.x >> 3);
    const int mb = tile >> 3;           // 32 m-blocks
    const int nb = tile & 7;            // 8 n-blocks
    const int wave = tid >> 6;          // 0..7
    const int lane = tid & 63;
    const int col  = lane & 15;
    const int quad = lane >> 4;
    const int m0 = mb * 128, n0 = nb * 128;
    const int wm = (wave & 1) * 64;     // 2 m-halves
    const int wn = (wave >> 1) * 32;    // 4 n-quarters of 32

    const int rr = lane >> 3;
    const int c8 = lane & 7;
    const int cx = c8 ^ rr;

    f32x4 acc[4][2];
    #pragma unroll
    for (int i = 0; i < 4; ++i)
        #pragma unroll
        for (int j = 0; j < 2; ++j) acc[i][j] = (f32x4){0.f,0.f,0.f,0.f};

    bf16x8 sa[2], sb[2];
    #pragma unroll
    for (int i = 0; i < 2; ++i) {
        int r = wave * 16 + i * 8 + rr;    // 0..127
        sa[i] = ldb8(Ain + (size_t)(m0 + r) * DD + c8 * 8);
        sb[i] = ldb8(W + (size_t)(n0 + r) * DD + c8 * 8);
    }

    for (int k0 = 0; k0 < DD; k0 += 64) {
        __syncthreads();
        #pragma unroll
        for (int i = 0; i < 2; ++i) {
            int r = wave * 16 + i * 8 + rr;
            stb8(As + r * 64 + cx * 8, sa[i]);
            stb8(Bs + r * 64 + cx * 8, sb[i]);
        }
        __syncthreads();
        if (k0 + 64 < DD) {
            #pragma unroll
            for (int i = 0; i < 2; ++i) {
                int r = wave * 16 + i * 8 + rr;
                sa[i] = ldb8(Ain + (size_t)(m0 + r) * DD + k0 + 64 + c8 * 8);
                sb[i] = ldb8(W + (size_t)(n0 + r) * DD + k0 + 64 + c8 * 8);
            }
        }

        #pragma unroll
        for (int kk = 0; kk < 2; ++kk) {
            bf16x8 af[4], bfv[2];
            #pragma unroll
            for (int ms = 0; ms < 4; ++ms) {
                int R = wm + ms * 16 + col;
                af[ms] = ldb8(As + R * 64 + (((kk * 4 + quad) ^ (R & 7)) * 8));
            }
            #pragma unroll
            for (int ns = 0; ns < 2; ++ns) {
                int R = wn + ns * 16 + col;
                bfv[ns] = ldb8(Bs + R * 64 + (((kk * 4 + quad) ^ (R & 7)) * 8));
            }
            #pragma unroll
            for (int ms = 0; ms < 4; ++ms)
                #pragma unroll
                for (int ns = 0; ns < 2; ++ns)
                    acc[ms][ns] = __builtin_amdgcn_mfma_f32_16x16x32_bf16(
                                      af[ms], bfv[ns], acc[ms][ns], 0, 0, 0);
        }
    }

    float bi[2];
    #pragma unroll
    for (int ns = 0; ns < 2; ++ns) bi[ns] = bias[n0 + wn + ns * 16 + col];

    __syncthreads();   // done with As/Bs before St reuse
    #pragma unroll
    for (int ms = 0; ms < 4; ++ms) {
        #pragma unroll
        for (int reg = 0; reg < 4; ++reg) {
            int r  = wm + ms * 16 + quad * 4 + reg;   // local m-row 0..127
            int sw = (r & 3) << 2;                    // XOR on 4-elem f32 chunks
            St[r * 128 + ((wn + col +  0) ^ sw)] = acc[ms][0][reg] + bi[0];
            St[r * 128 + ((wn + col + 16) ^ sw)] = acc[ms][1][reg] + bi[1];
        }
    }
    __syncthreads();
    #pragma unroll
    for (int j = 0; j < 8; ++j) {
        int row = j * 16 + (tid >> 5);                // 0..127
        int c4  = (tid & 31) * 4;
        float4 vv = *(const float4*)(const void*)(St + row * 128 + (c4 ^ ((row & 3) << 2)));
        *(float4*)(void*)(out + (size_t)(m0 + row) * DD + n0 + c4) = vv;
    }
}

extern "C" void kernel_launch(void* const* d_in, const int* in_sizes, int n_in,
                              void* d_out, int out_size, void* d_ws, size_t ws_size,
                              hipStream_t stream) {
    const float* q     = (const float*)d_in[0];
    const float* k     = (const float*)d_in[1];
    const float* v     = (const float*)d_in[2];
    const float* freqs = (const float*)d_in[3];
    const float* Wq = (const float*)d_in[4];
    const float* bq = (const float*)d_in[5];
    const float* Wk = (const float*)d_in[6];
    const float* bk = (const float*)d_in[7];
    const float* Wv = (const float*)d_in[8];
    const float* bv = (const float*)d_in[9];
    const float* Wo = (const float*)d_in[10];
    const float* bo = (const float*)d_in[11];
    float* out = (float*)d_out;

    const size_t welems = (size_t)DD * DD;             // 1M
    const size_t elems  = (size_t)BB * HH * LL * HDIM; // 4M (= B*L*D)
    bf16* Wqb = (bf16*)d_ws;
    bf16* Wkb = Wqb + welems;
    bf16* Wvb = Wkb + welems;
    bf16* Wob = Wvb + welems;
    bf16* qb  = Wob + welems;
    bf16* kb  = qb + elems;
    bf16* vb  = kb + elems;
    bf16* Qr  = vb + elems;
    bf16* Kr  = Qr + elems;
    bf16* Vt  = Kr + elems;   // V^T [B*H, HD, L]
    bf16* Obf = Vt + elems;   // O [B, L, D]; total ws: 8 + 24 + 32 = 64 MB

    cvt_all<<<dim3(16384), dim3(256), 0, stream>>>(Wq, Wk, Wv, Wo, q, k, v,
                                                   Wqb, Wkb, Wvb, Wob, qb, kb, vb);
    qkv3_gemm<<<dim3(3072), dim3(256), 0, stream>>>(qb, kb, vb, Wqb, Wkb, Wvb,
                                                    bq, bk, bv, freqs, Qr, Kr, Vt);
    attn_mfma<<<dim3(BB * HH * (LL / 256)), dim3(512), 0, stream>>>(Qr, Kr, Vt, Obf);
    out_gemm<<<dim3(256), dim3(512), 0, stream>>>(Obf, Wob, bo, out);
}